// Round 1
// baseline (44.565 us; speedup 1.0000x reference)
//
#include <hip/hip_runtime.h>
#include <hip/hip_bf16.h>

// StreamingConv == GEMM: C[b,o] = sum_k A[b,k] * W[o,k]
//   A = curr_input [256][16384] f32 row-major (K-contiguous)
//   W = weight     [1024][16384] f32 row-major (K-contiguous)  -> B^T layout
// Strategy: bf16 MFMA (16x16x32) with on-the-fly f32->bf16 conversion,
// split-K (16) + f32 hardware atomics, double-buffered LDS, padded to kill
// bank conflicts.

#define B_DIM 256
#define CO    1024
#define KTOT  16384          // C_IN * K = 1024 * 16
#define BM    64
#define BN    64
#define BK    64
#define SPLITK 16
#define KC    (KTOT / SPLITK)   // 1024
#define KITERS (KC / BK)        // 16
#define SA    (BK + 8)          // LDS row stride in bf16 elems: 72 -> 144B (2-way max conflict)

typedef __attribute__((ext_vector_type(8))) short  short8;   // 8 bf16 = 4 VGPR (MFMA A/B frag)
typedef __attribute__((ext_vector_type(4))) float  f32x4;    // MFMA C/D frag
typedef __attribute__((ext_vector_type(4))) unsigned short u16x4;

__device__ __forceinline__ unsigned short f2bf(float f) {
    // native fptrunc -> bf16 (gfx950 has v_cvt_pk_bf16_f32; let compiler pick)
    union { __bf16 h; unsigned short u; } cv;
    cv.h = (__bf16)f;
    return cv.u;
}

__global__ __launch_bounds__(256, 4)
void sconv_gemm(const float* __restrict__ A, const float* __restrict__ W,
                float* __restrict__ out) {
    __shared__ unsigned short lA[2][BM * SA];
    __shared__ unsigned short lB[2][BN * SA];

    const int tid = threadIdx.x;
    const int bm = (blockIdx.x >> 4) * BM;   // 4 M-tiles
    const int bn = (blockIdx.x & 15) * BN;   // 16 N-tiles
    const int k0 = blockIdx.y * KC;          // split-K chunk

    const float* Abase = A + (size_t)bm * KTOT + k0;
    const float* Wbase = W + (size_t)bn * KTOT + k0;

    // staging decomposition: 64 rows x 16 float4 per tile = 1024 float4; 4/thread
    int srow[4], sq[4];
    #pragma unroll
    for (int i = 0; i < 4; ++i) {
        int idx = i * 256 + tid;
        srow[i] = idx >> 4;
        sq[i]   = (idx & 15) * 4;
    }

    float4 ra[4], rw[4];
    // prologue: load k-tile 0
    #pragma unroll
    for (int i = 0; i < 4; ++i) {
        ra[i] = *(const float4*)(Abase + (size_t)srow[i] * KTOT + sq[i]);
        rw[i] = *(const float4*)(Wbase + (size_t)srow[i] * KTOT + sq[i]);
    }
    #pragma unroll
    for (int i = 0; i < 4; ++i) {
        u16x4 pa, pw;
        pa.x = f2bf(ra[i].x); pa.y = f2bf(ra[i].y); pa.z = f2bf(ra[i].z); pa.w = f2bf(ra[i].w);
        pw.x = f2bf(rw[i].x); pw.y = f2bf(rw[i].y); pw.z = f2bf(rw[i].z); pw.w = f2bf(rw[i].w);
        *(u16x4*)(&lA[0][srow[i] * SA + sq[i]]) = pa;
        *(u16x4*)(&lB[0][srow[i] * SA + sq[i]]) = pw;
    }

    // wave -> 32x32 sub-tile of the 64x64 block tile (2x2 wave grid)
    const int wid  = tid >> 6;
    const int lane = tid & 63;
    const int wm = (wid >> 1) * 32;
    const int wn = (wid & 1) * 32;
    const int frow = lane & 15;          // fragment row (A) / col (B)
    const int fk   = (lane >> 4) * 8;    // fragment k-offset

    f32x4 acc[2][2] = {};

    int cur = 0;
    for (int t = 0; t < KITERS; ++t) {
        // issue next k-tile's global loads early (overlap with MFMA below)
        if (t + 1 < KITERS) {
            const float* Ab = Abase + (t + 1) * BK;
            const float* Wb = Wbase + (t + 1) * BK;
            #pragma unroll
            for (int i = 0; i < 4; ++i) {
                ra[i] = *(const float4*)(Ab + (size_t)srow[i] * KTOT + sq[i]);
                rw[i] = *(const float4*)(Wb + (size_t)srow[i] * KTOT + sq[i]);
            }
        }

        __syncthreads();   // lds[cur] writes (prev iter) visible to all waves

        #pragma unroll
        for (int kk = 0; kk < 2; ++kk) {
            short8 af[2], bfr[2];
            #pragma unroll
            for (int mi = 0; mi < 2; ++mi)
                af[mi] = *(const short8*)(&lA[cur][(wm + mi * 16 + frow) * SA + kk * 32 + fk]);
            #pragma unroll
            for (int ni = 0; ni < 2; ++ni)
                bfr[ni] = *(const short8*)(&lB[cur][(wn + ni * 16 + frow) * SA + kk * 32 + fk]);
            #pragma unroll
            for (int mi = 0; mi < 2; ++mi)
                #pragma unroll
                for (int ni = 0; ni < 2; ++ni)
                    acc[mi][ni] = __builtin_amdgcn_mfma_f32_16x16x32_bf16(
                        af[mi], bfr[ni], acc[mi][ni], 0, 0, 0);
        }

        // convert + write next tile into the other buffer (no barrier needed:
        // everyone already finished reading buf cur^1 before the barrier above)
        if (t + 1 < KITERS) {
            #pragma unroll
            for (int i = 0; i < 4; ++i) {
                u16x4 pa, pw;
                pa.x = f2bf(ra[i].x); pa.y = f2bf(ra[i].y); pa.z = f2bf(ra[i].z); pa.w = f2bf(ra[i].w);
                pw.x = f2bf(rw[i].x); pw.y = f2bf(rw[i].y); pw.z = f2bf(rw[i].z); pw.w = f2bf(rw[i].w);
                *(u16x4*)(&lA[cur ^ 1][srow[i] * SA + sq[i]]) = pa;
                *(u16x4*)(&lB[cur ^ 1][srow[i] * SA + sq[i]]) = pw;
            }
        }
        cur ^= 1;
    }

    // epilogue: C/D layout for 16x16x32: col = lane&15, row = (lane>>4)*4 + j
    const int crow = (lane >> 4) * 4;
    const int ccol = lane & 15;
    #pragma unroll
    for (int mi = 0; mi < 2; ++mi) {
        const int gr = bm + wm + mi * 16 + crow;
        #pragma unroll
        for (int ni = 0; ni < 2; ++ni) {
            const int gc = bn + wn + ni * 16 + ccol;
            #pragma unroll
            for (int j = 0; j < 4; ++j) {
                unsafeAtomicAdd(out + (size_t)(gr + j) * CO + gc, acc[mi][ni][j]);
            }
        }
    }
}

extern "C" void kernel_launch(void* const* d_in, const int* in_sizes, int n_in,
                              void* d_out, int out_size, void* d_ws, size_t ws_size,
                              hipStream_t stream) {
    const float* A = (const float*)d_in[0];   // curr_input [256][1024][16]
    const float* W = (const float*)d_in[1];   // weight     [1024][1024][16]
    float* out = (float*)d_out;               // [256][1024] f32

    hipMemsetAsync(d_out, 0, (size_t)out_size * sizeof(float), stream);

    dim3 grid(4 * 16, SPLITK);  // (M-tiles * N-tiles, split-K)
    sconv_gemm<<<grid, 256, 0, stream>>>(A, W, out);
}

// Round 2
// 41.249 us; speedup vs baseline: 1.0804x; 1.0804x over previous
//
#include <hip/hip_runtime.h>
#include <hip/hip_bf16.h>

// StreamingConv == GEMM: C[b,o] = sum_k A[b,k] * W[o,k]
//   A = curr_input [256][16384] f32 row-major (K-contiguous)
//   W = weight     [1024][16384] f32 row-major (K-contiguous)  -> B^T layout
// bf16 MFMA (16x16x32), on-the-fly f32->bf16, split-K(16).
// R2: atomics were the bottleneck (WRITE_SIZE == 4.19M atomics * 4B, dur
// unchanged with L3-warm inputs) -> split-K partials to d_ws + reduce kernel.

#define B_DIM 256
#define CO    1024
#define KTOT  16384          // C_IN * K = 1024 * 16
#define BM    64
#define BN    64
#define BK    64
#define SPLITK 16
#define KC    (KTOT / SPLITK)   // 1024
#define KITERS (KC / BK)        // 16
#define SA    (BK + 8)          // LDS row stride (bf16): 144B -> 2-way max conflict (free)
#define OUT_ELEMS (B_DIM * CO)  // 262144

typedef __attribute__((ext_vector_type(8))) short  short8;   // MFMA A/B frag
typedef __attribute__((ext_vector_type(4))) float  f32x4;    // MFMA C/D frag
typedef __attribute__((ext_vector_type(4))) unsigned short u16x4;

__device__ __forceinline__ unsigned short f2bf(float f) {
    union { __bf16 h; unsigned short u; } cv;
    cv.h = (__bf16)f;
    return cv.u;
}

template <bool USE_WS>
__global__ __launch_bounds__(256, 4)
void sconv_gemm(const float* __restrict__ A, const float* __restrict__ W,
                float* __restrict__ out, float* __restrict__ ws) {
    __shared__ unsigned short lA[2][BM * SA];
    __shared__ unsigned short lB[2][BN * SA];

    const int tid = threadIdx.x;
    const int bm = (blockIdx.x >> 4) * BM;   // 4 M-tiles
    const int bn = (blockIdx.x & 15) * BN;   // 16 N-tiles
    const int k0 = blockIdx.y * KC;          // split-K chunk

    const float* Abase = A + (size_t)bm * KTOT + k0;
    const float* Wbase = W + (size_t)bn * KTOT + k0;

    // staging: 64 rows x 16 float4 per tile = 1024 float4; 4/thread
    int srow[4], sq[4];
    #pragma unroll
    for (int i = 0; i < 4; ++i) {
        int idx = i * 256 + tid;
        srow[i] = idx >> 4;
        sq[i]   = (idx & 15) * 4;
    }

    float4 ra[4], rw[4];
    #pragma unroll
    for (int i = 0; i < 4; ++i) {
        ra[i] = *(const float4*)(Abase + (size_t)srow[i] * KTOT + sq[i]);
        rw[i] = *(const float4*)(Wbase + (size_t)srow[i] * KTOT + sq[i]);
    }
    #pragma unroll
    for (int i = 0; i < 4; ++i) {
        u16x4 pa, pw;
        pa.x = f2bf(ra[i].x); pa.y = f2bf(ra[i].y); pa.z = f2bf(ra[i].z); pa.w = f2bf(ra[i].w);
        pw.x = f2bf(rw[i].x); pw.y = f2bf(rw[i].y); pw.z = f2bf(rw[i].z); pw.w = f2bf(rw[i].w);
        *(u16x4*)(&lA[0][srow[i] * SA + sq[i]]) = pa;
        *(u16x4*)(&lB[0][srow[i] * SA + sq[i]]) = pw;
    }

    // wave -> 32x32 sub-tile of the 64x64 block tile (2x2 wave grid)
    const int wid  = tid >> 6;
    const int lane = tid & 63;
    const int wm = (wid >> 1) * 32;
    const int wn = (wid & 1) * 32;
    const int frow = lane & 15;
    const int fk   = (lane >> 4) * 8;

    f32x4 acc[2][2] = {};

    int cur = 0;
    for (int t = 0; t < KITERS; ++t) {
        if (t + 1 < KITERS) {   // issue next k-tile loads early
            const float* Ab = Abase + (t + 1) * BK;
            const float* Wb = Wbase + (t + 1) * BK;
            #pragma unroll
            for (int i = 0; i < 4; ++i) {
                ra[i] = *(const float4*)(Ab + (size_t)srow[i] * KTOT + sq[i]);
                rw[i] = *(const float4*)(Wb + (size_t)srow[i] * KTOT + sq[i]);
            }
        }

        __syncthreads();

        #pragma unroll
        for (int kk = 0; kk < 2; ++kk) {
            short8 af[2], bfr[2];
            #pragma unroll
            for (int mi = 0; mi < 2; ++mi)
                af[mi] = *(const short8*)(&lA[cur][(wm + mi * 16 + frow) * SA + kk * 32 + fk]);
            #pragma unroll
            for (int ni = 0; ni < 2; ++ni)
                bfr[ni] = *(const short8*)(&lB[cur][(wn + ni * 16 + frow) * SA + kk * 32 + fk]);
            #pragma unroll
            for (int mi = 0; mi < 2; ++mi)
                #pragma unroll
                for (int ni = 0; ni < 2; ++ni)
                    acc[mi][ni] = __builtin_amdgcn_mfma_f32_16x16x32_bf16(
                        af[mi], bfr[ni], acc[mi][ni], 0, 0, 0);
        }

        if (t + 1 < KITERS) {
            #pragma unroll
            for (int i = 0; i < 4; ++i) {
                u16x4 pa, pw;
                pa.x = f2bf(ra[i].x); pa.y = f2bf(ra[i].y); pa.z = f2bf(ra[i].z); pa.w = f2bf(ra[i].w);
                pw.x = f2bf(rw[i].x); pw.y = f2bf(rw[i].y); pw.z = f2bf(rw[i].z); pw.w = f2bf(rw[i].w);
                *(u16x4*)(&lA[cur ^ 1][srow[i] * SA + sq[i]]) = pa;
                *(u16x4*)(&lB[cur ^ 1][srow[i] * SA + sq[i]]) = pw;
            }
        }
        cur ^= 1;
    }

    // epilogue: C/D layout 16x16x32: col = lane&15, row = (lane>>4)*4 + j
    const int crow = (lane >> 4) * 4;
    const int ccol = lane & 15;
    float* pout = USE_WS ? (ws + (size_t)blockIdx.y * OUT_ELEMS) : out;
    #pragma unroll
    for (int mi = 0; mi < 2; ++mi) {
        const int gr = bm + wm + mi * 16 + crow;
        #pragma unroll
        for (int ni = 0; ni < 2; ++ni) {
            const int gc = bn + wn + ni * 16 + ccol;
            #pragma unroll
            for (int j = 0; j < 4; ++j) {
                if (USE_WS) {
                    pout[(size_t)(gr + j) * CO + gc] = acc[mi][ni][j];
                } else {
                    unsafeAtomicAdd(pout + (size_t)(gr + j) * CO + gc, acc[mi][ni][j]);
                }
            }
        }
    }
}

// sum 16 split-K partial slices -> out.  65536 float4s, one per thread.
__global__ __launch_bounds__(256)
void reduce_splitk(const float* __restrict__ ws, float* __restrict__ out) {
    const int i = (blockIdx.x * 256 + threadIdx.x);   // float4 index
    const float4* p = (const float4*)ws + i;
    float4 s = p[0];
    #pragma unroll
    for (int sdx = 1; sdx < SPLITK; ++sdx) {
        float4 v = p[(size_t)sdx * (OUT_ELEMS / 4)];
        s.x += v.x; s.y += v.y; s.z += v.z; s.w += v.w;
    }
    ((float4*)out)[i] = s;
}

extern "C" void kernel_launch(void* const* d_in, const int* in_sizes, int n_in,
                              void* d_out, int out_size, void* d_ws, size_t ws_size,
                              hipStream_t stream) {
    const float* A = (const float*)d_in[0];   // curr_input [256][1024][16]
    const float* W = (const float*)d_in[1];   // weight     [1024][1024][16]
    float* out = (float*)d_out;               // [256][1024] f32
    float* ws  = (float*)d_ws;

    const size_t ws_needed = (size_t)SPLITK * OUT_ELEMS * sizeof(float); // 16.8 MB
    dim3 grid(4 * 16, SPLITK);

    if (ws_size >= ws_needed) {
        sconv_gemm<true><<<grid, 256, 0, stream>>>(A, W, out, ws);
        reduce_splitk<<<OUT_ELEMS / 4 / 256, 256, 0, stream>>>(ws, out);
    } else {
        hipMemsetAsync(d_out, 0, (size_t)out_size * sizeof(float), stream);
        sconv_gemm<false><<<grid, 256, 0, stream>>>(A, W, out, ws);
    }
}